// Round 8
// baseline (160.694 us; speedup 1.0000x reference)
//
#include <hip/hip_runtime.h>
#include <math.h>

// SimpleSSM: u(B,DI,L) f32, A(S), B_mat(S,DI), C_mat(DO,S), D_mat(DO,DI), h0(S)
#define BZ 8
#define DI 256
#define DS 512
#define DOUT 256
#define LL 4096
#define BS (BZ * DS)   // 4096
#define CH 64
#define CT 64
#define TST 136        // k_bu scan-tile LDS stride in ushorts

typedef __bf16 bf16x8 __attribute__((ext_vector_type(8)));
typedef float f32x4 __attribute__((ext_vector_type(4)));
typedef unsigned short us8 __attribute__((ext_vector_type(8)));

__device__ __forceinline__ ushort f2b(float f) {
    union { float f; unsigned u; } v; v.f = f;
    unsigned r = v.u + 0x7FFFu + ((v.u >> 16) & 1u);
    return (ushort)(r >> 16);
}
__device__ __forceinline__ float b2f(ushort h) {
    union { unsigned u; float f; } v; v.u = ((unsigned)h) << 16;
    return v.f;
}

__device__ __forceinline__ void gload16(const ushort* g, ushort* l) {
    __builtin_amdgcn_global_load_lds(
        (const __attribute__((address_space(1))) unsigned int*)g,
        (__attribute__((address_space(3))) unsigned int*)l,
        16, 0, 0);
}

// ---------------------------------------------------------------------------
// k_prep_u2t: blocks [0,2048): u transpose+bf16; blocks [2048,2368): apow +
// bf16 conversion of Bm/Cm/Dm + D!=0 flag. Merged to save a launch.
// ---------------------------------------------------------------------------
__global__ __launch_bounds__(256) void k_prep_u2t(const float* __restrict__ u,
                                                  ushort* __restrict__ utr,
                                                  const float* __restrict__ Au,
                                                  float* __restrict__ apow,
                                                  const float* __restrict__ Bm,
                                                  const float* __restrict__ Cm,
                                                  const float* __restrict__ Dm,
                                                  ushort* __restrict__ Bmb,
                                                  ushort* __restrict__ Cmb,
                                                  ushort* __restrict__ Dmb,
                                                  int* __restrict__ dflag) {
    __shared__ float T[64][65];
    const int tid = threadIdx.x;
    const int id = blockIdx.x;
    if (id < 2048) {   // ---- u2t role
        const int l0 = (id & 63) * 64;
        const int i0 = ((id >> 6) & 3) * 64;
        const int b  = id >> 8;
        const int r = tid >> 4, c4 = tid & 15;
#pragma unroll
        for (int rr = r; rr < 64; rr += 16) {
            float4 v = *(const float4*)&u[((size_t)b * DI + i0 + rr) * LL + l0 + c4 * 4];
            T[rr][c4 * 4 + 0] = v.x; T[rr][c4 * 4 + 1] = v.y;
            T[rr][c4 * 4 + 2] = v.z; T[rr][c4 * 4 + 3] = v.w;
        }
        __syncthreads();
#pragma unroll
        for (int ll = r; ll < 64; ll += 16) {
            ushort4 o;
            o.x = f2b(T[c4 * 4 + 0][ll]); o.y = f2b(T[c4 * 4 + 1][ll]);
            o.z = f2b(T[c4 * 4 + 2][ll]); o.w = f2b(T[c4 * 4 + 3][ll]);
            *(ushort4*)&utr[((size_t)b * LL + l0 + ll) * DI + i0 + c4 * 4] = o;
        }
    } else {           // ---- prep role
        const int t = (id - 2048) * 256 + tid;
        const int n1 = DS * DI / 4, n2 = DOUT * DS / 4, n3 = DOUT * DI / 4;
        if (t < n1) {
            float4 v = ((const float4*)Bm)[t];
            ushort4 o; o.x = f2b(v.x); o.y = f2b(v.y); o.z = f2b(v.z); o.w = f2b(v.w);
            ((ushort4*)Bmb)[t] = o;
        } else if (t < n1 + n2) {
            float4 v = ((const float4*)Cm)[t - n1];
            ushort4 o; o.x = f2b(v.x); o.y = f2b(v.y); o.z = f2b(v.z); o.w = f2b(v.w);
            ((ushort4*)Cmb)[t - n1] = o;
        } else if (t < n1 + n2 + n3) {
            float4 v = ((const float4*)Dm)[t - n1 - n2];
            ushort4 o; o.x = f2b(v.x); o.y = f2b(v.y); o.z = f2b(v.z); o.w = f2b(v.w);
            ((ushort4*)Dmb)[t - n1 - n2] = o;
            if (v.x != 0.f || v.y != 0.f || v.z != 0.f || v.w != 0.f)
                atomicOr(dflag, 1);
        }
        if (t < DS) {
            float x = Au[t];
            float sp = (x > 15.f) ? x : log1pf(expf(x));
            float ad = -sp;
            float p = 1.f;
            apow[t] = 1.f;
            for (int j = 1; j <= CT; ++j) { p *= ad; apow[j * DS + t] = p; }
        }
    }
}

// ---------------------------------------------------------------------------
// k_bu: Xb = local-scanned(B @ u) + finals. Single-barrier dbuf K-loop.
// ---------------------------------------------------------------------------
__global__ __launch_bounds__(256) void k_bu(const ushort* __restrict__ Bmb,
                                            const ushort* __restrict__ utr,
                                            ushort* __restrict__ Xb,
                                            float* __restrict__ finals,
                                            const float* __restrict__ apow) {
    __shared__ ushort smem[128 * TST];   // 34.8 KB; GEMM dbuf = first 32 KB
    const int tid = threadIdx.x;
    const int w = tid >> 6, lane = tid & 63;
    const int l0 = blockIdx.x * 128, s0 = blockIdx.y * 128, b = blockIdx.z;
    const int wm = w & 1, wn = w >> 1;
    const int mrow = lane & 15, quad = lane >> 4;
    const int sr = lane >> 2, sc = (lane & 3) * 8;
    const int off0 = (16 * w) * 32, off1 = (16 * w + 64) * 32;

    f32x4 acc[4][4];
#pragma unroll
    for (int mi = 0; mi < 4; ++mi)
#pragma unroll
        for (int ni = 0; ni < 4; ++ni) acc[mi][ni] = (f32x4)0.f;

    const ushort* ag0 = Bmb + (size_t)(s0 + 16 * w + sr) * DI + sc;
    const ushort* ag1 = ag0 + (size_t)64 * DI;
    const ushort* bg0 = utr + ((size_t)b * LL + l0 + 16 * w + sr) * DI + sc;
    const ushort* bg1 = bg0 + (size_t)64 * DI;

    gload16(ag0, smem + off0); gload16(ag1, smem + off1);
    gload16(bg0, smem + 8192 + off0); gload16(bg1, smem + 8192 + off1);

    for (int it = 0; it < DI / 32; ++it) {
        __syncthreads();
        const int cb = (it & 1) * 4096, nb = 4096 - cb;
        if (it + 1 < DI / 32) {
            const int kk = (it + 1) * 32;
            gload16(ag0 + kk, smem + nb + off0); gload16(ag1 + kk, smem + nb + off1);
            gload16(bg0 + kk, smem + 8192 + nb + off0); gload16(bg1 + kk, smem + 8192 + nb + off1);
        }
        bf16x8 af[4], bfr[4];
#pragma unroll
        for (int mi = 0; mi < 4; ++mi)
            af[mi] = *(const bf16x8*)&smem[cb + (wm * 64 + mi * 16 + mrow) * 32 + quad * 8];
#pragma unroll
        for (int ni = 0; ni < 4; ++ni)
            bfr[ni] = *(const bf16x8*)&smem[8192 + cb + (wn * 64 + ni * 16 + mrow) * 32 + quad * 8];
#pragma unroll
        for (int mi = 0; mi < 4; ++mi)
#pragma unroll
            for (int ni = 0; ni < 4; ++ni)
                acc[mi][ni] = __builtin_amdgcn_mfma_f32_16x16x32_bf16(af[mi], bfr[ni], acc[mi][ni], 0, 0, 0);
    }
    __syncthreads();

#pragma unroll
    for (int mi = 0; mi < 4; ++mi) {
        const int sloc = wm * 64 + mi * 16 + quad * 4;
#pragma unroll
        for (int ni = 0; ni < 4; ++ni) {
            const int lloc = wn * 64 + ni * 16 + mrow;
            f32x4 v = acc[mi][ni];
            ushort4 o; o.x = f2b(v[0]); o.y = f2b(v[1]); o.z = f2b(v[2]); o.w = f2b(v[3]);
            *(ushort4*)&smem[lloc * TST + sloc] = o;
        }
    }
    __syncthreads();
    {
        const int cloc = tid >> 7, sl = tid & 127;
        const float a = apow[DS + s0 + sl];
        float acc2 = 0.f;
        ushort* p = &smem[(cloc * 64) * TST + sl];
#pragma unroll 8
        for (int j = 0; j < CT; ++j) {
            acc2 = a * acc2 + b2f(*p);
            *p = f2b(acc2);
            p += TST;
        }
        finals[(size_t)(l0 / 64 + cloc) * BS + (size_t)b * DS + s0 + sl] = acc2;
    }
    __syncthreads();
    {
        const int rr = tid >> 4, cc = tid & 15;
#pragma unroll
        for (int rep = 0; rep < 8; ++rep) {
            const int l = rep * 16 + rr;
            us8 v = *(const us8*)&smem[l * TST + cc * 8];
            *(us8*)&Xb[(size_t)(l0 + l) * BS + (size_t)b * DS + s0 + cc * 8] = v;
        }
    }
}

// ---------------------------------------------------------------------------
// k_out: Y = C @ (X + a^{j+1} carry) [+ D @ u if D != 0].
// Carries for this block's 2 time-chunks recomputed in-block from finals
// (same fp32 op order as the old k_carry -> bit-identical), stored in LDS.
// ---------------------------------------------------------------------------
__global__ __launch_bounds__(256) void k_out(const ushort* __restrict__ Cmb,
                                             const ushort* __restrict__ Dmb,
                                             const ushort* __restrict__ Xb,
                                             const ushort* __restrict__ utr,
                                             const float* __restrict__ finals,
                                             const float* __restrict__ apow,
                                             const float* __restrict__ h0,
                                             const int* __restrict__ dflag,
                                             float* __restrict__ Y) {
    __shared__ ushort smem[20480];   // 41 KB: GEMM bufs [0,18432) + carries 4 KB
    float* crs = (float*)&smem[18432];   // crs[0..511]=carry(c0), [512..1023]=carry(c0+1)
    const int tid = threadIdx.x;
    const int w = tid >> 6, lane = tid & 63;
    const int l0 = blockIdx.x * 128, o0 = blockIdx.y * 128, b = blockIdx.z;
    const int wm = w & 1, wn = w >> 1;
    const int mrow = lane & 15, quad = lane >> 4;
    const int sr = lane >> 2, sc = (lane & 3) * 8;
    const int off0 = (16 * w) * 32, off1 = (16 * w + 64) * 32;
    const int dnz = *dflag;

    f32x4 acc[4][4];
#pragma unroll
    for (int mi = 0; mi < 4; ++mi)
#pragma unroll
        for (int ni = 0; ni < 4; ++ni) acc[mi][ni] = (f32x4)0.f;

    auto compute = [&](const int aoff, const int ast, const int boff) {
        bf16x8 af[4], bfr[4];
#pragma unroll
        for (int mi = 0; mi < 4; ++mi)
            af[mi] = *(const bf16x8*)&smem[aoff + (wm * 64 + mi * 16 + mrow) * ast + quad * 8];
#pragma unroll
        for (int ni = 0; ni < 4; ++ni)
            bfr[ni] = *(const bf16x8*)&smem[boff + (wn * 64 + ni * 16 + mrow) * 32 + quad * 8];
#pragma unroll
        for (int mi = 0; mi < 4; ++mi)
#pragma unroll
            for (int ni = 0; ni < 4; ++ni)
                acc[mi][ni] = __builtin_amdgcn_mfma_f32_16x16x32_bf16(af[mi], bfr[ni], acc[mi][ni], 0, 0, 0);
    };

    { // phase 1: C @ X_corrected, K = DS, 16 iters
        const int r0 = 16 * w + sr;
        const int l_0 = l0 + r0, l_1 = l_0 + 64;
        const int j0 = l_0 & 63;
        const int j1 = l_1 & 63;
        const int c0 = l0 >> 6;                 // block's first chunk
        const float* ap0 = &apow[(size_t)(j0 + 1) * DS];
        const float* ap1 = &apow[(size_t)(j1 + 1) * DS];
        const ushort* x0 = Xb + (size_t)l_0 * BS + (size_t)b * DS;
        const ushort* x1 = Xb + (size_t)l_1 * BS + (size_t)b * DS;
        const ushort* bg0 = Cmb + (size_t)(o0 + r0) * DS + sc;
        const ushort* bg1 = bg0 + (size_t)64 * DS;

        // B prologue first (async, disjoint LDS region) to overlap carry compute
        gload16(bg0, smem + 10240 + off0); gload16(bg1, smem + 10240 + off1);

        // in-block carry recomputation (bit-identical to old k_carry chain)
        for (int s = tid; s < DS; s += 256) {
            const float aT = apow[CT * DS + s];
            float carry = h0[s];
            const float* fb = finals + (size_t)b * DS + s;
            for (int c = 0; c < c0; ++c)
                carry = aT * carry + fb[(size_t)c * BS];
            crs[s] = carry;
            crs[DS + s] = aT * carry + fb[(size_t)c0 * BS];
        }
        __syncthreads();    // crs ready for stageA

        auto stageA = [&](int it, int dstoff) {
            const int col = it * 32 + sc;
            {
                us8 x = *(const us8*)&x0[col];
                float4 pa = *(const float4*)&ap0[col], pb = *(const float4*)&ap0[col + 4];
                float4 ca = *(const float4*)&crs[col], cb = *(const float4*)&crs[col + 4];
                us8 o;
                o[0] = f2b(b2f(x[0]) + pa.x * ca.x); o[1] = f2b(b2f(x[1]) + pa.y * ca.y);
                o[2] = f2b(b2f(x[2]) + pa.z * ca.z); o[3] = f2b(b2f(x[3]) + pa.w * ca.w);
                o[4] = f2b(b2f(x[4]) + pb.x * cb.x); o[5] = f2b(b2f(x[5]) + pb.y * cb.y);
                o[6] = f2b(b2f(x[6]) + pb.z * cb.z); o[7] = f2b(b2f(x[7]) + pb.w * cb.w);
                *(us8*)&smem[dstoff + r0 * 40 + sc] = o;
            }
            {
                us8 x = *(const us8*)&x1[col];
                float4 pa = *(const float4*)&ap1[col], pb = *(const float4*)&ap1[col + 4];
                float4 ca = *(const float4*)&crs[DS + col], cb = *(const float4*)&crs[DS + col + 4];
                us8 o;
                o[0] = f2b(b2f(x[0]) + pa.x * ca.x); o[1] = f2b(b2f(x[1]) + pa.y * ca.y);
                o[2] = f2b(b2f(x[2]) + pa.z * ca.z); o[3] = f2b(b2f(x[3]) + pa.w * ca.w);
                o[4] = f2b(b2f(x[4]) + pb.x * cb.x); o[5] = f2b(b2f(x[5]) + pb.y * cb.y);
                o[6] = f2b(b2f(x[6]) + pb.z * cb.z); o[7] = f2b(b2f(x[7]) + pb.w * cb.w);
                *(us8*)&smem[dstoff + (r0 + 64) * 40 + sc] = o;
            }
        };

        stageA(0, 0);

        for (int it = 0; it < DS / 32; ++it) {
            __syncthreads();
            const int ca_ = (it & 1) * 5120, na_ = 5120 - ca_;
            const int cb_ = 10240 + (it & 1) * 4096, nb_ = 10240 + 4096 - (it & 1) * 4096;
            if (it + 1 < DS / 32) {
                const int kk = (it + 1) * 32;
                gload16(bg0 + kk, smem + nb_ + off0); gload16(bg1 + kk, smem + nb_ + off1);
                stageA(it + 1, na_);
            }
            compute(ca_, 40, cb_);
        }
    }
    if (dnz) { // phase 2: D @ u, K = DI, 8 iters — only when D has nonzeros
        const ushort* ag0 = utr + ((size_t)b * LL + l0 + 16 * w + sr) * DI + sc;
        const ushort* ag1 = ag0 + (size_t)64 * DI;
        const ushort* bg0 = Dmb + (size_t)(o0 + 16 * w + sr) * DI + sc;
        const ushort* bg1 = bg0 + (size_t)64 * DI;

        __syncthreads();
        gload16(ag0, smem + off0); gload16(ag1, smem + off1);
        gload16(bg0, smem + 10240 + off0); gload16(bg1, smem + 10240 + off1);

        for (int it = 0; it < DI / 32; ++it) {
            __syncthreads();
            const int ca_ = (it & 1) * 5120, na_ = 5120 - ca_;
            const int cb_ = 10240 + (it & 1) * 4096, nb_ = 10240 + 4096 - (it & 1) * 4096;
            if (it + 1 < DI / 32) {
                const int kk = (it + 1) * 32;
                gload16(ag0 + kk, smem + na_ + off0); gload16(ag1 + kk, smem + na_ + off1);
                gload16(bg0 + kk, smem + nb_ + off0); gload16(bg1 + kk, smem + nb_ + off1);
            }
            compute(ca_, 32, cb_);
        }
    }

#pragma unroll
    for (int mi = 0; mi < 4; ++mi) {
        const int l = l0 + wm * 64 + mi * 16 + quad * 4;
#pragma unroll
        for (int ni = 0; ni < 4; ++ni) {
            const int o = o0 + wn * 64 + ni * 16 + mrow;
            *(float4*)&Y[((size_t)b * DOUT + o) * LL + l] = *(float4*)&acc[mi][ni];
        }
    }
}

// ---------------------------------------------------------------------------
extern "C" void kernel_launch(void* const* d_in, const int* in_sizes, int n_in,
                              void* d_out, int out_size, void* d_ws, size_t ws_size,
                              hipStream_t stream) {
    const float* u  = (const float*)d_in[0];
    const float* Au = (const float*)d_in[1];
    const float* Bm = (const float*)d_in[2];
    const float* Cm = (const float*)d_in[3];
    const float* Dm = (const float*)d_in[4];
    const float* h0 = (const float*)d_in[5];
    float* Y = (float*)d_out;

    char* p = (char*)d_ws;
    ushort* utr    = (ushort*)p; p += (size_t)BZ * LL * DI * 2;
    ushort* Xb     = (ushort*)p; p += (size_t)LL * BS * 2;
    float* finals  = (float*)p;  p += (size_t)CH * BS * 4;
    float* apow    = (float*)p;  p += (size_t)(CT + 1) * DS * 4;
    ushort* Bmb    = (ushort*)p; p += (size_t)DS * DI * 2;
    ushort* Cmb    = (ushort*)p; p += (size_t)DOUT * DS * 2;
    ushort* Dmb    = (ushort*)p; p += (size_t)DOUT * DI * 2;
    int* dflag     = (int*)p;    p += 16;

    hipMemsetAsync(dflag, 0, 4, stream);
    k_prep_u2t<<<dim3(2368), 256, 0, stream>>>(u, utr, Au, apow, Bm, Cm, Dm, Bmb, Cmb, Dmb, dflag);
    k_bu<<<dim3(LL / 128, DS / 128, BZ), 256, 0, stream>>>(Bmb, utr, Xb, finals, apow);
    k_out<<<dim3(LL / 128, DOUT / 128, BZ), 256, 0, stream>>>(Cmb, Dmb, Xb, utr, finals, apow, h0, dflag, Y);
}

// Round 9
// 146.008 us; speedup vs baseline: 1.1006x; 1.1006x over previous
//
#include <hip/hip_runtime.h>
#include <math.h>

// SimpleSSM: u(B,DI,L) f32, A(S), B_mat(S,DI), C_mat(DO,S), D_mat(DO,DI), h0(S)
#define BZ 8
#define DI 256
#define DS 512
#define DOUT 256
#define LL 4096
#define BS (BZ * DS)   // 4096
#define CH 64
#define CT 64
#define TST 136        // k_bu scan-tile LDS stride in ushorts

typedef __bf16 bf16x8 __attribute__((ext_vector_type(8)));
typedef float f32x4 __attribute__((ext_vector_type(4)));
typedef unsigned short us8 __attribute__((ext_vector_type(8)));

__device__ __forceinline__ ushort f2b(float f) {
    union { float f; unsigned u; } v; v.f = f;
    unsigned r = v.u + 0x7FFFu + ((v.u >> 16) & 1u);
    return (ushort)(r >> 16);
}
__device__ __forceinline__ float b2f(ushort h) {
    union { unsigned u; float f; } v; v.u = ((unsigned)h) << 16;
    return v.f;
}

__device__ __forceinline__ void gload16(const ushort* g, ushort* l) {
    __builtin_amdgcn_global_load_lds(
        (const __attribute__((address_space(1))) unsigned int*)g,
        (__attribute__((address_space(3))) unsigned int*)l,
        16, 0, 0);
}

// ---------------------------------------------------------------------------
// k_prep_u2t: blocks [0,2048): u transpose+bf16; blocks [2048,2368): apow +
// bf16 conversion of Bm/Cm/Dm + D!=0 flag.
// ---------------------------------------------------------------------------
__global__ __launch_bounds__(256) void k_prep_u2t(const float* __restrict__ u,
                                                  ushort* __restrict__ utr,
                                                  const float* __restrict__ Au,
                                                  float* __restrict__ apow,
                                                  const float* __restrict__ Bm,
                                                  const float* __restrict__ Cm,
                                                  const float* __restrict__ Dm,
                                                  ushort* __restrict__ Bmb,
                                                  ushort* __restrict__ Cmb,
                                                  ushort* __restrict__ Dmb,
                                                  int* __restrict__ dflag) {
    __shared__ float T[64][65];
    const int tid = threadIdx.x;
    const int id = blockIdx.x;
    if (id < 2048) {   // ---- u2t role
        const int l0 = (id & 63) * 64;
        const int i0 = ((id >> 6) & 3) * 64;
        const int b  = id >> 8;
        const int r = tid >> 4, c4 = tid & 15;
#pragma unroll
        for (int rr = r; rr < 64; rr += 16) {
            float4 v = *(const float4*)&u[((size_t)b * DI + i0 + rr) * LL + l0 + c4 * 4];
            T[rr][c4 * 4 + 0] = v.x; T[rr][c4 * 4 + 1] = v.y;
            T[rr][c4 * 4 + 2] = v.z; T[rr][c4 * 4 + 3] = v.w;
        }
        __syncthreads();
#pragma unroll
        for (int ll = r; ll < 64; ll += 16) {
            ushort4 o;
            o.x = f2b(T[c4 * 4 + 0][ll]); o.y = f2b(T[c4 * 4 + 1][ll]);
            o.z = f2b(T[c4 * 4 + 2][ll]); o.w = f2b(T[c4 * 4 + 3][ll]);
            *(ushort4*)&utr[((size_t)b * LL + l0 + ll) * DI + i0 + c4 * 4] = o;
        }
    } else {           // ---- prep role
        const int t = (id - 2048) * 256 + tid;
        const int n1 = DS * DI / 4, n2 = DOUT * DS / 4, n3 = DOUT * DI / 4;
        if (t < n1) {
            float4 v = ((const float4*)Bm)[t];
            ushort4 o; o.x = f2b(v.x); o.y = f2b(v.y); o.z = f2b(v.z); o.w = f2b(v.w);
            ((ushort4*)Bmb)[t] = o;
        } else if (t < n1 + n2) {
            float4 v = ((const float4*)Cm)[t - n1];
            ushort4 o; o.x = f2b(v.x); o.y = f2b(v.y); o.z = f2b(v.z); o.w = f2b(v.w);
            ((ushort4*)Cmb)[t - n1] = o;
        } else if (t < n1 + n2 + n3) {
            float4 v = ((const float4*)Dm)[t - n1 - n2];
            ushort4 o; o.x = f2b(v.x); o.y = f2b(v.y); o.z = f2b(v.z); o.w = f2b(v.w);
            ((ushort4*)Dmb)[t - n1 - n2] = o;
            if (v.x != 0.f || v.y != 0.f || v.z != 0.f || v.w != 0.f)
                atomicOr(dflag, 1);
        }
        if (t < DS) {
            float x = Au[t];
            float sp = (x > 15.f) ? x : log1pf(expf(x));
            float ad = -sp;
            float p = 1.f;
            apow[t] = 1.f;
            for (int j = 1; j <= CT; ++j) { p *= ad; apow[j * DS + t] = p; }
        }
    }
}

// ---------------------------------------------------------------------------
// k_bu: Xb = local-scanned(B @ u) + finals. Single-barrier dbuf K-loop.
// ---------------------------------------------------------------------------
__global__ __launch_bounds__(256) void k_bu(const ushort* __restrict__ Bmb,
                                            const ushort* __restrict__ utr,
                                            ushort* __restrict__ Xb,
                                            float* __restrict__ finals,
                                            const float* __restrict__ apow) {
    __shared__ ushort smem[128 * TST];   // 34.8 KB; GEMM dbuf = first 32 KB
    const int tid = threadIdx.x;
    const int w = tid >> 6, lane = tid & 63;
    const int l0 = blockIdx.x * 128, s0 = blockIdx.y * 128, b = blockIdx.z;
    const int wm = w & 1, wn = w >> 1;
    const int mrow = lane & 15, quad = lane >> 4;
    const int sr = lane >> 2, sc = (lane & 3) * 8;
    const int off0 = (16 * w) * 32, off1 = (16 * w + 64) * 32;

    f32x4 acc[4][4];
#pragma unroll
    for (int mi = 0; mi < 4; ++mi)
#pragma unroll
        for (int ni = 0; ni < 4; ++ni) acc[mi][ni] = (f32x4)0.f;

    const ushort* ag0 = Bmb + (size_t)(s0 + 16 * w + sr) * DI + sc;
    const ushort* ag1 = ag0 + (size_t)64 * DI;
    const ushort* bg0 = utr + ((size_t)b * LL + l0 + 16 * w + sr) * DI + sc;
    const ushort* bg1 = bg0 + (size_t)64 * DI;

    gload16(ag0, smem + off0); gload16(ag1, smem + off1);
    gload16(bg0, smem + 8192 + off0); gload16(bg1, smem + 8192 + off1);

    for (int it = 0; it < DI / 32; ++it) {
        __syncthreads();
        const int cb = (it & 1) * 4096, nb = 4096 - cb;
        if (it + 1 < DI / 32) {
            const int kk = (it + 1) * 32;
            gload16(ag0 + kk, smem + nb + off0); gload16(ag1 + kk, smem + nb + off1);
            gload16(bg0 + kk, smem + 8192 + nb + off0); gload16(bg1 + kk, smem + 8192 + nb + off1);
        }
        bf16x8 af[4], bfr[4];
#pragma unroll
        for (int mi = 0; mi < 4; ++mi)
            af[mi] = *(const bf16x8*)&smem[cb + (wm * 64 + mi * 16 + mrow) * 32 + quad * 8];
#pragma unroll
        for (int ni = 0; ni < 4; ++ni)
            bfr[ni] = *(const bf16x8*)&smem[8192 + cb + (wn * 64 + ni * 16 + mrow) * 32 + quad * 8];
#pragma unroll
        for (int mi = 0; mi < 4; ++mi)
#pragma unroll
            for (int ni = 0; ni < 4; ++ni)
                acc[mi][ni] = __builtin_amdgcn_mfma_f32_16x16x32_bf16(af[mi], bfr[ni], acc[mi][ni], 0, 0, 0);
    }
    __syncthreads();

#pragma unroll
    for (int mi = 0; mi < 4; ++mi) {
        const int sloc = wm * 64 + mi * 16 + quad * 4;
#pragma unroll
        for (int ni = 0; ni < 4; ++ni) {
            const int lloc = wn * 64 + ni * 16 + mrow;
            f32x4 v = acc[mi][ni];
            ushort4 o; o.x = f2b(v[0]); o.y = f2b(v[1]); o.z = f2b(v[2]); o.w = f2b(v[3]);
            *(ushort4*)&smem[lloc * TST + sloc] = o;
        }
    }
    __syncthreads();
    {
        const int cloc = tid >> 7, sl = tid & 127;
        const float a = apow[DS + s0 + sl];
        float acc2 = 0.f;
        ushort* p = &smem[(cloc * 64) * TST + sl];
#pragma unroll 8
        for (int j = 0; j < CT; ++j) {
            acc2 = a * acc2 + b2f(*p);
            *p = f2b(acc2);
            p += TST;
        }
        finals[(size_t)(l0 / 64 + cloc) * BS + (size_t)b * DS + s0 + sl] = acc2;
    }
    __syncthreads();
    {
        const int rr = tid >> 4, cc = tid & 15;
#pragma unroll
        for (int rep = 0; rep < 8; ++rep) {
            const int l = rep * 16 + rr;
            us8 v = *(const us8*)&smem[l * TST + cc * 8];
            *(us8*)&Xb[(size_t)(l0 + l) * BS + (size_t)b * DS + s0 + cc * 8] = v;
        }
    }
}

// ---------------------------------------------------------------------------
__global__ __launch_bounds__(256) void k_carry(const float* __restrict__ finals,
                                               float* __restrict__ carries,
                                               const float* __restrict__ apow,
                                               const float* __restrict__ h0) {
    const int bs = blockIdx.x * 256 + threadIdx.x;
    const int s = bs & (DS - 1);
    const float aT = apow[CT * DS + s];
    float carry = h0[s];
#pragma unroll 8
    for (int c = 0; c < CH; ++c) {
        carries[(size_t)c * BS + bs] = carry;
        carry = aT * carry + finals[(size_t)c * BS + bs];
    }
}

// ---------------------------------------------------------------------------
// k_out: Y = C @ (X + a^{j+1} carry) [+ D @ u if D != 0].
// Tile 64(l) x 128(o): 1024 blocks (4/CU), one time-chunk per block.
// LDS (ushort offs): A0=0, A1=2560 (stride 40); B0=5120, B1=9216 (stride 32).
// ---------------------------------------------------------------------------
__global__ __launch_bounds__(256) void k_out(const ushort* __restrict__ Cmb,
                                             const ushort* __restrict__ Dmb,
                                             const ushort* __restrict__ Xb,
                                             const ushort* __restrict__ utr,
                                             const float* __restrict__ carries,
                                             const float* __restrict__ apow,
                                             const int* __restrict__ dflag,
                                             float* __restrict__ Y) {
    __shared__ ushort smem[13312];   // 26.6 KB
    const int tid = threadIdx.x;
    const int w = tid >> 6, lane = tid & 63;
    const int l0 = blockIdx.x * 64, o0 = blockIdx.y * 128, b = blockIdx.z;
    const int mrow = lane & 15, quad = lane >> 4;
    const int sr = lane >> 2, sc = (lane & 3) * 8;
    const int off0 = (16 * w) * 32, off1 = (16 * w + 64) * 32;
    const int dnz = *dflag;

    f32x4 acc[4][2];
#pragma unroll
    for (int mi = 0; mi < 4; ++mi)
#pragma unroll
        for (int ni = 0; ni < 2; ++ni) acc[mi][ni] = (f32x4)0.f;

    // af rows = l (A-buf), bfr rows = o (B-buf); wave w covers o rows [32w,32w+32)
    auto compute = [&](const int aoff, const int ast, const int boff) {
        bf16x8 af[4], bfr[2];
#pragma unroll
        for (int mi = 0; mi < 4; ++mi)
            af[mi] = *(const bf16x8*)&smem[aoff + (mi * 16 + mrow) * ast + quad * 8];
#pragma unroll
        for (int ni = 0; ni < 2; ++ni)
            bfr[ni] = *(const bf16x8*)&smem[boff + (32 * w + ni * 16 + mrow) * 32 + quad * 8];
#pragma unroll
        for (int mi = 0; mi < 4; ++mi)
#pragma unroll
            for (int ni = 0; ni < 2; ++ni)
                acc[mi][ni] = __builtin_amdgcn_mfma_f32_16x16x32_bf16(af[mi], bfr[ni], acc[mi][ni], 0, 0, 0);
    };

    { // phase 1: C @ X_corrected, K = DS, 16 iters
        const int r0 = 16 * w + sr;              // 0..63 == chunk-local j
        const int c0 = l0 >> 6;                  // this block's (single) chunk
        const float* ap0 = &apow[(size_t)(r0 + 1) * DS];
        const float* cr0 = &carries[(size_t)c0 * BS + (size_t)b * DS];
        const ushort* x0 = Xb + (size_t)(l0 + r0) * BS + (size_t)b * DS;
        const ushort* bg0 = Cmb + (size_t)(o0 + r0) * DS + sc;
        const ushort* bg1 = bg0 + (size_t)64 * DS;

        auto stageA = [&](int it, int dstoff) {
            const int col = it * 32 + sc;
            us8 x = *(const us8*)&x0[col];
            float4 pa = *(const float4*)&ap0[col], pb = *(const float4*)&ap0[col + 4];
            float4 ca = *(const float4*)&cr0[col], cb = *(const float4*)&cr0[col + 4];
            us8 o;
            o[0] = f2b(b2f(x[0]) + pa.x * ca.x); o[1] = f2b(b2f(x[1]) + pa.y * ca.y);
            o[2] = f2b(b2f(x[2]) + pa.z * ca.z); o[3] = f2b(b2f(x[3]) + pa.w * ca.w);
            o[4] = f2b(b2f(x[4]) + pb.x * cb.x); o[5] = f2b(b2f(x[5]) + pb.y * cb.y);
            o[6] = f2b(b2f(x[6]) + pb.z * cb.z); o[7] = f2b(b2f(x[7]) + pb.w * cb.w);
            *(us8*)&smem[dstoff + r0 * 40 + sc] = o;
        };

        stageA(0, 0);
        gload16(bg0, smem + 5120 + off0); gload16(bg1, smem + 5120 + off1);

        for (int it = 0; it < DS / 32; ++it) {
            __syncthreads();
            const int ca_ = (it & 1) * 2560, na_ = 2560 - ca_;
            const int cb_ = 5120 + (it & 1) * 4096, nb_ = 5120 + 4096 - (it & 1) * 4096;
            if (it + 1 < DS / 32) {
                const int kk = (it + 1) * 32;
                gload16(bg0 + kk, smem + nb_ + off0); gload16(bg1 + kk, smem + nb_ + off1);
                stageA(it + 1, na_);
            }
            compute(ca_, 40, cb_);
        }
    }
    if (dnz) { // phase 2: D @ u, K = DI, 8 iters (A: 64 rows stride 32, 1 gload)
        const ushort* ag0 = utr + ((size_t)b * LL + l0 + 16 * w + sr) * DI + sc;
        const ushort* bg0 = Dmb + (size_t)(o0 + 16 * w + sr) * DI + sc;
        const ushort* bg1 = bg0 + (size_t)64 * DI;

        __syncthreads();
        gload16(ag0, smem + off0);
        gload16(bg0, smem + 5120 + off0); gload16(bg1, smem + 5120 + off1);

        for (int it = 0; it < DI / 32; ++it) {
            __syncthreads();
            const int ca_ = (it & 1) * 2560, na_ = 2560 - ca_;
            const int cb_ = 5120 + (it & 1) * 4096, nb_ = 5120 + 4096 - (it & 1) * 4096;
            if (it + 1 < DI / 32) {
                const int kk = (it + 1) * 32;
                gload16(ag0 + kk, smem + na_ + off0);
                gload16(bg0 + kk, smem + nb_ + off0); gload16(bg1 + kk, smem + nb_ + off1);
            }
            compute(ca_, 32, cb_);
        }
    }

#pragma unroll
    for (int mi = 0; mi < 4; ++mi) {
        const int l = l0 + mi * 16 + quad * 4;
#pragma unroll
        for (int ni = 0; ni < 2; ++ni) {
            const int o = o0 + 32 * w + ni * 16 + mrow;
            *(float4*)&Y[((size_t)b * DOUT + o) * LL + l] = *(float4*)&acc[mi][ni];
        }
    }
}

// ---------------------------------------------------------------------------
extern "C" void kernel_launch(void* const* d_in, const int* in_sizes, int n_in,
                              void* d_out, int out_size, void* d_ws, size_t ws_size,
                              hipStream_t stream) {
    const float* u  = (const float*)d_in[0];
    const float* Au = (const float*)d_in[1];
    const float* Bm = (const float*)d_in[2];
    const float* Cm = (const float*)d_in[3];
    const float* Dm = (const float*)d_in[4];
    const float* h0 = (const float*)d_in[5];
    float* Y = (float*)d_out;

    char* p = (char*)d_ws;
    ushort* utr    = (ushort*)p; p += (size_t)BZ * LL * DI * 2;
    ushort* Xb     = (ushort*)p; p += (size_t)LL * BS * 2;
    float* finals  = (float*)p;  p += (size_t)CH * BS * 4;
    float* carries = (float*)p;  p += (size_t)CH * BS * 4;
    float* apow    = (float*)p;  p += (size_t)(CT + 1) * DS * 4;
    ushort* Bmb    = (ushort*)p; p += (size_t)DS * DI * 2;
    ushort* Cmb    = (ushort*)p; p += (size_t)DOUT * DS * 2;
    ushort* Dmb    = (ushort*)p; p += (size_t)DOUT * DI * 2;
    int* dflag     = (int*)p;    p += 16;

    hipMemsetAsync(dflag, 0, 4, stream);
    k_prep_u2t<<<dim3(2368), 256, 0, stream>>>(u, utr, Au, apow, Bm, Cm, Dm, Bmb, Cmb, Dmb, dflag);
    k_bu<<<dim3(LL / 128, DS / 128, BZ), 256, 0, stream>>>(Bmb, utr, Xb, finals, apow);
    k_carry<<<dim3(BS / 256), 256, 0, stream>>>(finals, carries, apow, h0);
    k_out<<<dim3(LL / 64, DOUT / 128, BZ), 256, 0, stream>>>(Cmb, Dmb, Xb, utr, carries, apow, dflag, Y);
}

// Round 10
// 143.392 us; speedup vs baseline: 1.1207x; 1.0182x over previous
//
#include <hip/hip_runtime.h>
#include <math.h>

// SimpleSSM: u(B,DI,L) f32, A(S), B_mat(S,DI), C_mat(DO,S), D_mat(DO,DI), h0(S)
#define BZ 8
#define DI 256
#define DS 512
#define DOUT 256
#define LL 4096
#define BS (BZ * DS)   // 4096
#define CH 64
#define CT 64
#define TST 136        // k_bu scan-tile LDS stride in ushorts

typedef __bf16 bf16x8 __attribute__((ext_vector_type(8)));
typedef float f32x4 __attribute__((ext_vector_type(4)));
typedef unsigned short us8 __attribute__((ext_vector_type(8)));

__device__ __forceinline__ ushort f2b(float f) {
    union { float f; unsigned u; } v; v.f = f;
    unsigned r = v.u + 0x7FFFu + ((v.u >> 16) & 1u);
    return (ushort)(r >> 16);
}
__device__ __forceinline__ float b2f(ushort h) {
    union { unsigned u; float f; } v; v.u = ((unsigned)h) << 16;
    return v.f;
}

__device__ __forceinline__ void gload16(const ushort* g, ushort* l) {
    __builtin_amdgcn_global_load_lds(
        (const __attribute__((address_space(1))) unsigned int*)g,
        (__attribute__((address_space(3))) unsigned int*)l,
        16, 0, 0);
}

// ---------------------------------------------------------------------------
// k_prep_u2t: blocks [0,2048): u transpose+bf16; blocks [2048,2368): apow +
// bf16 conversion of Bm/Cm/Dm + D!=0 flag.
// ---------------------------------------------------------------------------
__global__ __launch_bounds__(256) void k_prep_u2t(const float* __restrict__ u,
                                                  ushort* __restrict__ utr,
                                                  const float* __restrict__ Au,
                                                  float* __restrict__ apow,
                                                  const float* __restrict__ Bm,
                                                  const float* __restrict__ Cm,
                                                  const float* __restrict__ Dm,
                                                  ushort* __restrict__ Bmb,
                                                  ushort* __restrict__ Cmb,
                                                  ushort* __restrict__ Dmb,
                                                  int* __restrict__ dflag) {
    __shared__ float T[64][65];
    const int tid = threadIdx.x;
    const int id = blockIdx.x;
    if (id < 2048) {   // ---- u2t role
        const int l0 = (id & 63) * 64;
        const int i0 = ((id >> 6) & 3) * 64;
        const int b  = id >> 8;
        const int r = tid >> 4, c4 = tid & 15;
#pragma unroll
        for (int rr = r; rr < 64; rr += 16) {
            float4 v = *(const float4*)&u[((size_t)b * DI + i0 + rr) * LL + l0 + c4 * 4];
            T[rr][c4 * 4 + 0] = v.x; T[rr][c4 * 4 + 1] = v.y;
            T[rr][c4 * 4 + 2] = v.z; T[rr][c4 * 4 + 3] = v.w;
        }
        __syncthreads();
#pragma unroll
        for (int ll = r; ll < 64; ll += 16) {
            ushort4 o;
            o.x = f2b(T[c4 * 4 + 0][ll]); o.y = f2b(T[c4 * 4 + 1][ll]);
            o.z = f2b(T[c4 * 4 + 2][ll]); o.w = f2b(T[c4 * 4 + 3][ll]);
            *(ushort4*)&utr[((size_t)b * LL + l0 + ll) * DI + i0 + c4 * 4] = o;
        }
    } else {           // ---- prep role
        const int t = (id - 2048) * 256 + tid;
        const int n1 = DS * DI / 4, n2 = DOUT * DS / 4, n3 = DOUT * DI / 4;
        if (t < n1) {
            float4 v = ((const float4*)Bm)[t];
            ushort4 o; o.x = f2b(v.x); o.y = f2b(v.y); o.z = f2b(v.z); o.w = f2b(v.w);
            ((ushort4*)Bmb)[t] = o;
        } else if (t < n1 + n2) {
            float4 v = ((const float4*)Cm)[t - n1];
            ushort4 o; o.x = f2b(v.x); o.y = f2b(v.y); o.z = f2b(v.z); o.w = f2b(v.w);
            ((ushort4*)Cmb)[t - n1] = o;
        } else if (t < n1 + n2 + n3) {
            float4 v = ((const float4*)Dm)[t - n1 - n2];
            ushort4 o; o.x = f2b(v.x); o.y = f2b(v.y); o.z = f2b(v.z); o.w = f2b(v.w);
            ((ushort4*)Dmb)[t - n1 - n2] = o;
            if (v.x != 0.f || v.y != 0.f || v.z != 0.f || v.w != 0.f)
                atomicOr(dflag, 1);
        }
        if (t < DS) {
            float x = Au[t];
            float sp = (x > 15.f) ? x : log1pf(expf(x));
            float ad = -sp;
            float p = 1.f;
            apow[t] = 1.f;
            for (int j = 1; j <= CT; ++j) { p *= ad; apow[j * DS + t] = p; }
        }
    }
}

// ---------------------------------------------------------------------------
// k_bu: Xb = local-scanned(B @ u) + finals. Single-barrier dbuf K-loop.
// ---------------------------------------------------------------------------
__global__ __launch_bounds__(256) void k_bu(const ushort* __restrict__ Bmb,
                                            const ushort* __restrict__ utr,
                                            ushort* __restrict__ Xb,
                                            float* __restrict__ finals,
                                            const float* __restrict__ apow) {
    __shared__ ushort smem[128 * TST];   // 34.8 KB; GEMM dbuf = first 32 KB
    const int tid = threadIdx.x;
    const int w = tid >> 6, lane = tid & 63;
    const int l0 = blockIdx.x * 128, s0 = blockIdx.y * 128, b = blockIdx.z;
    const int wm = w & 1, wn = w >> 1;
    const int mrow = lane & 15, quad = lane >> 4;
    const int sr = lane >> 2, sc = (lane & 3) * 8;
    const int off0 = (16 * w) * 32, off1 = (16 * w + 64) * 32;

    f32x4 acc[4][4];
#pragma unroll
    for (int mi = 0; mi < 4; ++mi)
#pragma unroll
        for (int ni = 0; ni < 4; ++ni) acc[mi][ni] = (f32x4)0.f;

    const ushort* ag0 = Bmb + (size_t)(s0 + 16 * w + sr) * DI + sc;
    const ushort* ag1 = ag0 + (size_t)64 * DI;
    const ushort* bg0 = utr + ((size_t)b * LL + l0 + 16 * w + sr) * DI + sc;
    const ushort* bg1 = bg0 + (size_t)64 * DI;

    gload16(ag0, smem + off0); gload16(ag1, smem + off1);
    gload16(bg0, smem + 8192 + off0); gload16(bg1, smem + 8192 + off1);

    for (int it = 0; it < DI / 32; ++it) {
        __syncthreads();
        const int cb = (it & 1) * 4096, nb = 4096 - cb;
        if (it + 1 < DI / 32) {
            const int kk = (it + 1) * 32;
            gload16(ag0 + kk, smem + nb + off0); gload16(ag1 + kk, smem + nb + off1);
            gload16(bg0 + kk, smem + 8192 + nb + off0); gload16(bg1 + kk, smem + 8192 + nb + off1);
        }
        bf16x8 af[4], bfr[4];
#pragma unroll
        for (int mi = 0; mi < 4; ++mi)
            af[mi] = *(const bf16x8*)&smem[cb + (wm * 64 + mi * 16 + mrow) * 32 + quad * 8];
#pragma unroll
        for (int ni = 0; ni < 4; ++ni)
            bfr[ni] = *(const bf16x8*)&smem[8192 + cb + (wn * 64 + ni * 16 + mrow) * 32 + quad * 8];
#pragma unroll
        for (int mi = 0; mi < 4; ++mi)
#pragma unroll
            for (int ni = 0; ni < 4; ++ni)
                acc[mi][ni] = __builtin_amdgcn_mfma_f32_16x16x32_bf16(af[mi], bfr[ni], acc[mi][ni], 0, 0, 0);
    }
    __syncthreads();

#pragma unroll
    for (int mi = 0; mi < 4; ++mi) {
        const int sloc = wm * 64 + mi * 16 + quad * 4;
#pragma unroll
        for (int ni = 0; ni < 4; ++ni) {
            const int lloc = wn * 64 + ni * 16 + mrow;
            f32x4 v = acc[mi][ni];
            ushort4 o; o.x = f2b(v[0]); o.y = f2b(v[1]); o.z = f2b(v[2]); o.w = f2b(v[3]);
            *(ushort4*)&smem[lloc * TST + sloc] = o;
        }
    }
    __syncthreads();
    {
        const int cloc = tid >> 7, sl = tid & 127;
        const float a = apow[DS + s0 + sl];
        float acc2 = 0.f;
        ushort* p = &smem[(cloc * 64) * TST + sl];
#pragma unroll 8
        for (int j = 0; j < CT; ++j) {
            acc2 = a * acc2 + b2f(*p);
            *p = f2b(acc2);
            p += TST;
        }
        finals[(size_t)(l0 / 64 + cloc) * BS + (size_t)b * DS + s0 + sl] = acc2;
    }
    __syncthreads();
    {
        const int rr = tid >> 4, cc = tid & 15;
#pragma unroll
        for (int rep = 0; rep < 8; ++rep) {
            const int l = rep * 16 + rr;
            us8 v = *(const us8*)&smem[l * TST + cc * 8];
            *(us8*)&Xb[(size_t)(l0 + l) * BS + (size_t)b * DS + s0 + cc * 8] = v;
        }
    }
}

// ---------------------------------------------------------------------------
__global__ __launch_bounds__(256) void k_carry(const float* __restrict__ finals,
                                               float* __restrict__ carries,
                                               const float* __restrict__ apow,
                                               const float* __restrict__ h0) {
    const int bs = blockIdx.x * 256 + threadIdx.x;
    const int s = bs & (DS - 1);
    const float aT = apow[CT * DS + s];
    float carry = h0[s];
#pragma unroll 8
    for (int c = 0; c < CH; ++c) {
        carries[(size_t)c * BS + bs] = carry;
        carry = aT * carry + finals[(size_t)c * BS + bs];
    }
}

// ---------------------------------------------------------------------------
// k_out: Y = C @ (X + a^{j+1} carry) [+ D @ u if D != 0].
// Tile 64(l) x 128(o), one time-chunk per block.
// Phase-1 A staged via REGISTER-PREFETCH pipeline: loads for it+1 issued
// before compute(it), converted+ds_written after compute(it) -> global-load
// latency hidden behind MFMA instead of exposed in the staging chain.
// LDS (ushort offs): A0=0, A1=2560 (stride 40); B0=5120, B1=9216 (stride 32).
// ---------------------------------------------------------------------------
__global__ __launch_bounds__(256) void k_out(const ushort* __restrict__ Cmb,
                                             const ushort* __restrict__ Dmb,
                                             const ushort* __restrict__ Xb,
                                             const ushort* __restrict__ utr,
                                             const float* __restrict__ carries,
                                             const float* __restrict__ apow,
                                             const int* __restrict__ dflag,
                                             float* __restrict__ Y) {
    __shared__ ushort smem[13312];   // 26.6 KB
    const int tid = threadIdx.x;
    const int w = tid >> 6, lane = tid & 63;
    const int l0 = blockIdx.x * 64, o0 = blockIdx.y * 128, b = blockIdx.z;
    const int mrow = lane & 15, quad = lane >> 4;
    const int sr = lane >> 2, sc = (lane & 3) * 8;
    const int off0 = (16 * w) * 32, off1 = (16 * w + 64) * 32;
    const int dnz = *dflag;

    f32x4 acc[4][2];
#pragma unroll
    for (int mi = 0; mi < 4; ++mi)
#pragma unroll
        for (int ni = 0; ni < 2; ++ni) acc[mi][ni] = (f32x4)0.f;

    auto compute = [&](const int aoff, const int ast, const int boff) {
        bf16x8 af[4], bfr[2];
#pragma unroll
        for (int mi = 0; mi < 4; ++mi)
            af[mi] = *(const bf16x8*)&smem[aoff + (mi * 16 + mrow) * ast + quad * 8];
#pragma unroll
        for (int ni = 0; ni < 2; ++ni)
            bfr[ni] = *(const bf16x8*)&smem[boff + (32 * w + ni * 16 + mrow) * 32 + quad * 8];
#pragma unroll
        for (int mi = 0; mi < 4; ++mi)
#pragma unroll
            for (int ni = 0; ni < 2; ++ni)
                acc[mi][ni] = __builtin_amdgcn_mfma_f32_16x16x32_bf16(af[mi], bfr[ni], acc[mi][ni], 0, 0, 0);
    };

    { // phase 1: C @ X_corrected, K = DS, 16 iters
        const int r0 = 16 * w + sr;              // 0..63 == chunk-local j
        const int c0 = l0 >> 6;                  // this block's (single) chunk
        const float* ap0 = &apow[(size_t)(r0 + 1) * DS];
        const float* cr0 = &carries[(size_t)c0 * BS + (size_t)b * DS];
        const ushort* x0 = Xb + (size_t)(l0 + r0) * BS + (size_t)b * DS;
        const ushort* bg0 = Cmb + (size_t)(o0 + r0) * DS + sc;
        const ushort* bg1 = bg0 + (size_t)64 * DS;

        // register prefetch state
        us8 xr; float4 par, pbr, car, cbr;
        auto loadX = [&](int it) {
            const int col = it * 32 + sc;
            xr  = *(const us8*)&x0[col];
            par = *(const float4*)&ap0[col];  pbr = *(const float4*)&ap0[col + 4];
            car = *(const float4*)&cr0[col];  cbr = *(const float4*)&cr0[col + 4];
        };
        auto storeA = [&](int dstoff) {
            us8 o;
            o[0] = f2b(b2f(xr[0]) + par.x * car.x); o[1] = f2b(b2f(xr[1]) + par.y * car.y);
            o[2] = f2b(b2f(xr[2]) + par.z * car.z); o[3] = f2b(b2f(xr[3]) + par.w * car.w);
            o[4] = f2b(b2f(xr[4]) + pbr.x * cbr.x); o[5] = f2b(b2f(xr[5]) + pbr.y * cbr.y);
            o[6] = f2b(b2f(xr[6]) + pbr.z * cbr.z); o[7] = f2b(b2f(xr[7]) + pbr.w * cbr.w);
            *(us8*)&smem[dstoff + r0 * 40 + sc] = o;
        };

        // prologue: buffer 0
        loadX(0); storeA(0);
        gload16(bg0, smem + 5120 + off0); gload16(bg1, smem + 5120 + off1);

        for (int it = 0; it < DS / 32; ++it) {
            __syncthreads();
            const int ca_ = (it & 1) * 2560, na_ = 2560 - ca_;
            const int cb_ = 5120 + (it & 1) * 4096, nb_ = 5120 + 4096 - (it & 1) * 4096;
            const bool more = (it + 1 < DS / 32);
            if (more) {
                const int kk = (it + 1) * 32;
                gload16(bg0 + kk, smem + nb_ + off0); gload16(bg1 + kk, smem + nb_ + off1);
                loadX(it + 1);            // issue loads; consumed only after compute
            }
            compute(ca_, 40, cb_);
            if (more) storeA(na_);        // convert + ds_write into alternate buffer
        }
    }
    if (dnz) { // phase 2: D @ u, K = DI, 8 iters (A: 64 rows stride 32, async)
        const ushort* ag0 = utr + ((size_t)b * LL + l0 + 16 * w + sr) * DI + sc;
        const ushort* bg0 = Dmb + (size_t)(o0 + 16 * w + sr) * DI + sc;
        const ushort* bg1 = bg0 + (size_t)64 * DI;

        __syncthreads();
        gload16(ag0, smem + off0);
        gload16(bg0, smem + 5120 + off0); gload16(bg1, smem + 5120 + off1);

        for (int it = 0; it < DI / 32; ++it) {
            __syncthreads();
            const int ca_ = (it & 1) * 2560, na_ = 2560 - ca_;
            const int cb_ = 5120 + (it & 1) * 4096, nb_ = 5120 + 4096 - (it & 1) * 4096;
            if (it + 1 < DI / 32) {
                const int kk = (it + 1) * 32;
                gload16(ag0 + kk, smem + na_ + off0);
                gload16(bg0 + kk, smem + nb_ + off0); gload16(bg1 + kk, smem + nb_ + off1);
            }
            compute(ca_, 32, cb_);
        }
    }

#pragma unroll
    for (int mi = 0; mi < 4; ++mi) {
        const int l = l0 + mi * 16 + quad * 4;
#pragma unroll
        for (int ni = 0; ni < 2; ++ni) {
            const int o = o0 + 32 * w + ni * 16 + mrow;
            *(float4*)&Y[((size_t)b * DOUT + o) * LL + l] = *(float4*)&acc[mi][ni];
        }
    }
}

// ---------------------------------------------------------------------------
extern "C" void kernel_launch(void* const* d_in, const int* in_sizes, int n_in,
                              void* d_out, int out_size, void* d_ws, size_t ws_size,
                              hipStream_t stream) {
    const float* u  = (const float*)d_in[0];
    const float* Au = (const float*)d_in[1];
    const float* Bm = (const float*)d_in[2];
    const float* Cm = (const float*)d_in[3];
    const float* Dm = (const float*)d_in[4];
    const float* h0 = (const float*)d_in[5];
    float* Y = (float*)d_out;

    char* p = (char*)d_ws;
    ushort* utr    = (ushort*)p; p += (size_t)BZ * LL * DI * 2;
    ushort* Xb     = (ushort*)p; p += (size_t)LL * BS * 2;
    float* finals  = (float*)p;  p += (size_t)CH * BS * 4;
    float* carries = (float*)p;  p += (size_t)CH * BS * 4;
    float* apow    = (float*)p;  p += (size_t)(CT + 1) * DS * 4;
    ushort* Bmb    = (ushort*)p; p += (size_t)DS * DI * 2;
    ushort* Cmb    = (ushort*)p; p += (size_t)DOUT * DS * 2;
    ushort* Dmb    = (ushort*)p; p += (size_t)DOUT * DI * 2;
    int* dflag     = (int*)p;    p += 16;

    hipMemsetAsync(dflag, 0, 4, stream);
    k_prep_u2t<<<dim3(2368), 256, 0, stream>>>(u, utr, Au, apow, Bm, Cm, Dm, Bmb, Cmb, Dmb, dflag);
    k_bu<<<dim3(LL / 128, DS / 128, BZ), 256, 0, stream>>>(Bmb, utr, Xb, finals, apow);
    k_carry<<<dim3(BS / 256), 256, 0, stream>>>(finals, carries, apow, h0);
    k_out<<<dim3(LL / 64, DOUT / 128, BZ), 256, 0, stream>>>(Cmb, Dmb, Xb, utr, carries, apow, dflag, Y);
}